// Round 2
// baseline (1284.187 us; speedup 1.0000x reference)
//
#include <hip/hip_runtime.h>
#include <stdint.h>

typedef unsigned int uint;
#define DEV __device__ __forceinline__

// ---------------- helpers ----------------

DEV int dot4(uint a, uint b, int c) {
#if __has_builtin(__builtin_amdgcn_sdot4)
    return __builtin_amdgcn_sdot4((int)a, (int)b, c, false);
#else
    int r = c;
    r += (int)(int8_t)(a)       * (int)(int8_t)(b);
    r += (int)(int8_t)(a >> 8)  * (int)(int8_t)(b >> 8);
    r += (int)(int8_t)(a >> 16) * (int)(int8_t)(b >> 16);
    r += (int)(int8_t)(a >> 24) * (int)(int8_t)(b >> 24);
    return r;
#endif
}

// requantize int32 accumulator -> relu'd integer in [0,127]
DEV uint requant_relu(int acc, float M) {
    float q = rintf((float)acc * M);          // jnp.round = round-half-even = rintf
    q = fminf(fmaxf(q, -127.f), 127.f);
    q = fmaxf(q, 0.f);
    return (uint)q;
}

// ---------------- kernel 0: quantize input to u8 ----------------
__global__ __launch_bounds__(256) void k_quant(const float* __restrict__ x,
                                               uint8_t* __restrict__ xq,
                                               float in_s) {
    int i = blockIdx.x * 256 + threadIdx.x;          // 1,048,576 threads, 4 elems each
    float4 v = ((const float4*)x)[i];
    uint b0 = (uint)fminf(fmaxf(rintf(v.x / in_s), 0.f), 255.f);
    uint b1 = (uint)fminf(fmaxf(rintf(v.y / in_s), 0.f), 255.f);
    uint b2 = (uint)fminf(fmaxf(rintf(v.z / in_s), 0.f), 255.f);
    uint b3 = (uint)fminf(fmaxf(rintf(v.w / in_s), 0.f), 255.f);
    ((uint*)xq)[i] = b0 | (b1 << 8) | (b2 << 16) | (b3 << 24);
}

// ---------------- layer 0: 1->16ch, 5x5, pad 2 ----------------
// grid (2, 512, 16), block 256. Output NHWC u8 (c=16).
__global__ __launch_bounds__(256) void k_l0(const uint8_t* __restrict__ xq,
                                            const int* __restrict__ w,
                                            const int* __restrict__ b,
                                            uint8_t* __restrict__ out, float M) {
    __shared__ int wl[16 * 25];
    __shared__ int bl[16];
    int t = threadIdx.x;
    for (int j = t; j < 400; j += 256) wl[j] = w[j] - 128;   // FIX: grid-stride (400 > 256)
    if (t < 16)  bl[t] = b[t];
    __syncthreads();
    int x0 = blockIdx.x * 256 + t;
    int y  = blockIdx.y;
    int n  = blockIdx.z;
    const uint8_t* xp = xq + (size_t)n * 512 * 512;
    int acc[16];
#pragma unroll
    for (int oc = 0; oc < 16; ++oc) acc[oc] = bl[oc];
#pragma unroll
    for (int dy = -2; dy <= 2; ++dy) {
        int yy = y + dy;
        bool yok = (unsigned)yy < 512u;
#pragma unroll
        for (int dx = -2; dx <= 2; ++dx) {
            int xx = x0 + dx;
            int v = (yok && (unsigned)xx < 512u) ? (int)xp[yy * 512 + xx] : 0;
            int p = (dy + 2) * 5 + (dx + 2);
#pragma unroll
            for (int oc = 0; oc < 16; ++oc) acc[oc] += v * wl[oc * 25 + p];
        }
    }
    uint dw[4];
#pragma unroll
    for (int g = 0; g < 4; ++g) {
        uint d = 0;
#pragma unroll
        for (int k = 0; k < 4; ++k) d |= requant_relu(acc[g * 4 + k], M) << (8 * k);
        dw[g] = d;
    }
    size_t pix = (size_t)(n * 512 + y) * 512 + x0;
    ((uint4*)out)[pix] = make_uint4(dw[0], dw[1], dw[2], dw[3]);
}

// ---------------- 1x1 layers (L1: 16->12, L6: 12->16) ----------------
template <int IC, int OC>
__global__ __launch_bounds__(256) void k_1x1(const uint8_t* __restrict__ in,
                                             const int* __restrict__ w,
                                             const int* __restrict__ b,
                                             uint8_t* __restrict__ out, float M) {
    constexpr int ICD = IC / 4;
    constexpr int OCD = OC / 4;
    __shared__ uint wl[OC * ICD];
    __shared__ int  bl[OC];
    int t = threadIdx.x;
    for (int j = t; j < OC * ICD; j += 256) {
        int oc = j / ICD, d = j % ICD;
        uint pk = 0;
#pragma unroll
        for (int k = 0; k < 4; ++k) {
            int wv = w[oc * IC + d * 4 + k] - 128;
            pk |= ((uint)(uint8_t)(int8_t)wv) << (8 * k);
        }
        wl[j] = pk;
    }
    if (t < OC) bl[t] = b[t];
    __syncthreads();
    size_t pix = (size_t)blockIdx.x * 256 + t;   // 4,194,304 pixels exactly
    uint a[ICD];
#pragma unroll
    for (int d = 0; d < ICD; ++d) a[d] = ((const uint*)in)[pix * ICD + d];
    uint dws[OCD];
#pragma unroll
    for (int g = 0; g < OCD; ++g) {
        uint dword = 0;
#pragma unroll
        for (int k = 0; k < 4; ++k) {
            int oc = g * 4 + k;
            int acc = bl[oc];
#pragma unroll
            for (int d = 0; d < ICD; ++d) acc = dot4(a[d], wl[oc * ICD + d], acc);
            dword |= requant_relu(acc, M) << (8 * k);
        }
        dws[g] = dword;
    }
#pragma unroll
    for (int g = 0; g < OCD; ++g) ((uint*)out)[pix * OCD + g] = dws[g];
}

// ---------------- 3x3 layers (12->12, pad 1) ----------------
// grid (512 rows, 16 imgs), block 128 threads, each thread 4 pixels.
__global__ __launch_bounds__(128) void k_3x3(const uint8_t* __restrict__ in,
                                             const int* __restrict__ w,
                                             const int* __restrict__ b,
                                             uint8_t* __restrict__ out, float M) {
    __shared__ uint wl[324];    // [pos][oc][d] packed i8 (ic 4 per dword)
    __shared__ int  bl[12];
    int t = threadIdx.x;
    for (int j = t; j < 324; j += 128) {
        int pos = j / 36;
        int oc  = (j % 36) / 3;
        int d   = j % 3;
        uint pk = 0;
#pragma unroll
        for (int k = 0; k < 4; ++k) {
            int ic = d * 4 + k;
            int wv = w[oc * 108 + ic * 9 + pos] - 128;
            pk |= ((uint)(uint8_t)(int8_t)wv) << (8 * k);
        }
        wl[j] = pk;
    }
    if (t < 12) bl[t] = b[t];
    __syncthreads();

    int y = blockIdx.x, n = blockIdx.y;
    int x0 = t * 4;                       // 128*4 = 512, exact cover
    const uint* ip = (const uint*)in;

    uint inr[3][6][3];
#pragma unroll
    for (int r = 0; r < 3; ++r) {
        int yy = y - 1 + r;
        bool yok = (unsigned)yy < 512u;
#pragma unroll
        for (int cidx = 0; cidx < 6; ++cidx) {
            int xx = x0 - 1 + cidx;
            bool ok = yok && (unsigned)xx < 512u;
            size_t base = ((size_t)(n * 512 + yy) * 512 + xx) * 3;
#pragma unroll
            for (int d = 0; d < 3; ++d) inr[r][cidx][d] = ok ? ip[base + d] : 0u;
        }
    }

    int acc[4][12];
#pragma unroll
    for (int p = 0; p < 4; ++p)
#pragma unroll
        for (int oc = 0; oc < 12; ++oc) acc[p][oc] = bl[oc];

#pragma unroll
    for (int ry = 0; ry < 3; ++ry) {
#pragma unroll
        for (int rx = 0; rx < 3; ++rx) {
            int pos = ry * 3 + rx;
#pragma unroll
            for (int oc = 0; oc < 12; ++oc) {
                uint w0 = wl[(pos * 12 + oc) * 3 + 0];
                uint w1 = wl[(pos * 12 + oc) * 3 + 1];
                uint w2 = wl[(pos * 12 + oc) * 3 + 2];
#pragma unroll
                for (int p = 0; p < 4; ++p) {
                    acc[p][oc] = dot4(inr[ry][rx + p][0], w0, acc[p][oc]);
                    acc[p][oc] = dot4(inr[ry][rx + p][1], w1, acc[p][oc]);
                    acc[p][oc] = dot4(inr[ry][rx + p][2], w2, acc[p][oc]);
                }
            }
        }
    }

#pragma unroll
    for (int p = 0; p < 4; ++p) {
        uint dws[3];
#pragma unroll
        for (int g = 0; g < 3; ++g) {
            uint dword = 0;
#pragma unroll
            for (int k = 0; k < 4; ++k) dword |= requant_relu(acc[p][g * 4 + k], M) << (8 * k);
            dws[g] = dword;
        }
        size_t pix = (size_t)(n * 512 + y) * 512 + (x0 + p);
        uint* op = (uint*)out;
        op[pix * 3 + 0] = dws[0];
        op[pix * 3 + 1] = dws[1];
        op[pix * 3 + 2] = dws[2];
    }
}

// ---------------- deconv: ConvTranspose2d(16,1,k=9,s=4,p=4) ----------------
// out (16, 2045, 2045) float. grid (8, 2045, 16), block 256.
__global__ __launch_bounds__(256) void k_deconv(const uint8_t* __restrict__ in,
                                                const float* __restrict__ wt,
                                                float* __restrict__ out,
                                                float out_s) {
    __shared__ float wl[1296];   // [ky][kx][c], flipped kernel
    int t = threadIdx.x;
    for (int j = t; j < 1296; j += 256) {
        int c = j & 15;
        int kykx = j >> 4;
        int ky = kykx / 9, kx = kykx % 9;
        wl[j] = wt[c * 81 + (8 - ky) * 9 + (8 - kx)];
    }
    __syncthreads();
    int ox = blockIdx.x * 256 + t;
    if (ox >= 2045) return;
    int oy = blockIdx.y, n = blockIdx.z;
    int sy = (4 - (oy & 3)) & 3;
    int sx = (4 - (ox & 3)) & 3;
    float acc = 0.f;
    for (int ky = sy; ky < 9; ky += 4) {
        int iy = (oy + ky - 4) >> 2;
        if ((unsigned)iy >= 512u) continue;
        for (int kx = sx; kx < 9; kx += 4) {
            int ix = (ox + kx - 4) >> 2;
            if ((unsigned)ix >= 512u) continue;
            uint4 a = ((const uint4*)in)[(size_t)(n * 512 + iy) * 512 + ix];
            const float* wp = &wl[(ky * 9 + kx) * 16];
            float s;
            s  = (float)( a.x        & 0xff) * wp[0];
            s += (float)((a.x >> 8)  & 0xff) * wp[1];
            s += (float)((a.x >> 16) & 0xff) * wp[2];
            s += (float)((a.x >> 24) & 0xff) * wp[3];
            s += (float)( a.y        & 0xff) * wp[4];
            s += (float)((a.y >> 8)  & 0xff) * wp[5];
            s += (float)((a.y >> 16) & 0xff) * wp[6];
            s += (float)((a.y >> 24) & 0xff) * wp[7];
            s += (float)( a.z        & 0xff) * wp[8];
            s += (float)((a.z >> 8)  & 0xff) * wp[9];
            s += (float)((a.z >> 16) & 0xff) * wp[10];
            s += (float)((a.z >> 24) & 0xff) * wp[11];
            s += (float)( a.w        & 0xff) * wp[12];
            s += (float)((a.w >> 8)  & 0xff) * wp[13];
            s += (float)((a.w >> 16) & 0xff) * wp[14];
            s += (float)((a.w >> 24) & 0xff) * wp[15];
            acc += s;
        }
    }
    out[((size_t)n * 2045 + oy) * 2045 + ox] = acc * out_s;
}

// ---------------- host launch ----------------
extern "C" void kernel_launch(void* const* d_in, const int* in_sizes, int n_in,
                              void* d_out, int out_size, void* d_ws, size_t ws_size,
                              hipStream_t stream) {
    const float* x  = (const float*)d_in[0];
    const int*   w0 = (const int*)d_in[1];
    const int*   b0 = (const int*)d_in[2];
    const int*   w1 = (const int*)d_in[3];
    const int*   b1 = (const int*)d_in[4];
    const int*   w2 = (const int*)d_in[5];
    const int*   b2 = (const int*)d_in[6];
    const int*   w3 = (const int*)d_in[7];
    const int*   b3 = (const int*)d_in[8];
    const int*   w4 = (const int*)d_in[9];
    const int*   b4 = (const int*)d_in[10];
    const int*   w5 = (const int*)d_in[11];
    const int*   b5 = (const int*)d_in[12];
    const int*   w6 = (const int*)d_in[13];
    const int*   b6 = (const int*)d_in[14];
    const float* wt = (const float*)d_in[15];
    float* out = (float*)d_out;

    uint8_t* A  = (uint8_t*)d_ws;                       // 64 MiB (NHWC c=16 or c=12)
    uint8_t* B  = (uint8_t*)d_ws + (size_t)(64 << 20);  // 64 MiB
    uint8_t* xq = B;                                    // xq dead after L0; reuse B

    // requant multipliers, computed in double then cast — bit-matches JAX scalar
    const float M0  = (float)((1.0 / 255.0) * 0.02 / 0.05);
    const float M1  = (float)(0.05 * 0.02 / 0.04);
    const float M25 = (float)(0.04 * 0.02 / 0.04);
    const float M6  = (float)(0.04 * 0.02 / 0.05);
    const float IN_S_F = (float)(1.0 / 255.0);

    k_quant<<<4096, 256, 0, stream>>>(x, xq, IN_S_F);
    k_l0<<<dim3(2, 512, 16), 256, 0, stream>>>(xq, w0, b0, A, M0);
    k_1x1<16, 12><<<16384, 256, 0, stream>>>(A, w1, b1, B, M1);
    k_3x3<<<dim3(512, 16), 128, 0, stream>>>(B, w2, b2, A, M25);
    k_3x3<<<dim3(512, 16), 128, 0, stream>>>(A, w3, b3, B, M25);
    k_3x3<<<dim3(512, 16), 128, 0, stream>>>(B, w4, b4, A, M25);
    k_3x3<<<dim3(512, 16), 128, 0, stream>>>(A, w5, b5, B, M25);
    k_1x1<12, 16><<<16384, 256, 0, stream>>>(B, w6, b6, A, M6);
    k_deconv<<<dim3(8, 2045, 16), 256, 0, stream>>>(A, wt, out, 0.05f);
}